// Round 1
// baseline (741.663 us; speedup 1.0000x reference)
//
#include <hip/hip_runtime.h>

// Problem constants (fixed by the reference file)
constexpr int cN1  = 100000;   // num_dst layer 1
constexpr int cN2  = 50000;    // num_dst layer 2
constexpr int cE0  = 1600000;
constexpr int cE1  = 800000;
constexpr int cIN  = 128;      // IN_F
constexpr int cH   = 256;      // H_F
constexpr int cCLS = 64;       // N_CLS

// -------- CSR row-start construction: dst is sorted, lower_bound per dst --------
__global__ void build_rows(const int* __restrict__ dst, int E, int num_dst,
                           int* __restrict__ row_start) {
    int d = blockIdx.x * blockDim.x + threadIdx.x;
    if (d > num_dst) return;
    int lo = 0, hi = E;
    while (lo < hi) {
        int mid = (lo + hi) >> 1;
        if (dst[mid] < d) lo = mid + 1; else hi = mid;
    }
    row_start[d] = lo;
}

// -------- Fused SAGE layer: aggregate + [self|neigh] GEMM + bias (+ReLU) --------
// One block handles BM=16 destination rows and all N output columns.
template<int K, int N, bool RELU>
__global__ void sage_layer(const float* __restrict__ hsrc,      // [n_src][K]
                           const int*   __restrict__ src_idx,   // [E]
                           const int*   __restrict__ row_start, // [num_dst+1]
                           const float* __restrict__ Wself,     // [K][N]
                           const float* __restrict__ Wneigh,    // [K][N]
                           const float* __restrict__ bias,      // [N]
                           float*       __restrict__ out,       // [num_dst][N]
                           int num_dst) {
    constexpr int BM = 16;
    constexpr int K4 = K / 4;       // float4s per feature row
    constexpr int NJ = K4 / 16;     // float4s per lane in aggregation (16 lanes/row)

    __shared__ float a_self[BM][K];
    __shared__ float a_neigh[BM][K];

    const int tid = threadIdx.x;
    const int m0  = blockIdx.x * BM;
    const float4* hs4 = (const float4*)hsrc;

    // ---- Stage self features (coalesced float4) ----
    #pragma unroll
    for (int j = 0; j < (BM * K4) / 256; ++j) {
        int idx = tid + j * 256;
        int r = idx / K4, k4 = idx % K4;
        int m = m0 + r;
        float4 v = make_float4(0.f, 0.f, 0.f, 0.f);
        if (m < num_dst) v = hs4[(size_t)m * K4 + k4];
        *(float4*)&a_self[r][k4 * 4] = v;
    }

    // ---- Mean-aggregate neighbors: 16 lanes per dst row ----
    {
        const int g = tid >> 4;      // which of the 16 rows
        const int t = tid & 15;      // lane within the row-group
        const int m = m0 + g;
        float4 acc[NJ];
        #pragma unroll
        for (int j = 0; j < NJ; ++j) acc[j] = make_float4(0.f, 0.f, 0.f, 0.f);
        int deg = 0;
        if (m < num_dst) {
            const int e0 = row_start[m], e1 = row_start[m + 1];
            deg = e1 - e0;
            for (int e = e0; e < e1; ++e) {
                const int s = src_idx[e];
                const float4* rowp = hs4 + (size_t)s * K4 + t;
                #pragma unroll
                for (int j = 0; j < NJ; ++j) {
                    float4 v = rowp[j * 16];
                    acc[j].x += v.x; acc[j].y += v.y; acc[j].z += v.z; acc[j].w += v.w;
                }
            }
        }
        const float inv = 1.0f / (float)(deg > 1 ? deg : 1);
        #pragma unroll
        for (int j = 0; j < NJ; ++j) {
            float4 v = make_float4(acc[j].x * inv, acc[j].y * inv,
                                   acc[j].z * inv, acc[j].w * inv);
            *(float4*)&a_neigh[g][(t + j * 16) * 4] = v;
        }
    }
    __syncthreads();

    // ---- Register-tiled GEMM: C[16][N] = Aself@Wself + Aneigh@Wneigh ----
    constexpr int TN   = 4;
    constexpr int COLG = N / TN;        // 64 (layer1) or 16 (layer2)
    constexpr int ROWG = 256 / COLG;    // 4 or 16
    constexpr int TM   = BM / ROWG;     // 4 or 1
    const int cg = tid % COLG;
    const int rg = tid / COLG;

    float acc[TM][TN];
    #pragma unroll
    for (int im = 0; im < TM; ++im)
        #pragma unroll
        for (int jn = 0; jn < TN; ++jn) acc[im][jn] = 0.f;

    for (int k = 0; k < K; k += 4) {
        float4 as[TM], an[TM];
        #pragma unroll
        for (int im = 0; im < TM; ++im) {
            const int r = rg * TM + im;
            as[im] = *(const float4*)&a_self[r][k];
            an[im] = *(const float4*)&a_neigh[r][k];
        }
        #pragma unroll
        for (int kk = 0; kk < 4; ++kk) {
            const float4 ws = *(const float4*)&Wself[(k + kk) * N + cg * TN];
            const float4 wn = *(const float4*)&Wneigh[(k + kk) * N + cg * TN];
            #pragma unroll
            for (int im = 0; im < TM; ++im) {
                const float a0 = (&as[im].x)[kk];
                const float a1 = (&an[im].x)[kk];
                acc[im][0] += a0 * ws.x + a1 * wn.x;
                acc[im][1] += a0 * ws.y + a1 * wn.y;
                acc[im][2] += a0 * ws.z + a1 * wn.z;
                acc[im][3] += a0 * ws.w + a1 * wn.w;
            }
        }
    }

    const float4 bv = *(const float4*)&bias[cg * TN];
    #pragma unroll
    for (int im = 0; im < TM; ++im) {
        const int m = m0 + rg * TM + im;
        if (m >= num_dst) continue;
        float4 o;
        o.x = acc[im][0] + bv.x;
        o.y = acc[im][1] + bv.y;
        o.z = acc[im][2] + bv.z;
        o.w = acc[im][3] + bv.w;
        if (RELU) {
            o.x = fmaxf(o.x, 0.f); o.y = fmaxf(o.y, 0.f);
            o.z = fmaxf(o.z, 0.f); o.w = fmaxf(o.w, 0.f);
        }
        *(float4*)&out[(size_t)m * N + cg * TN] = o;
    }
}

extern "C" void kernel_launch(void* const* d_in, const int* in_sizes, int n_in,
                              void* d_out, int out_size, void* d_ws, size_t ws_size,
                              hipStream_t stream) {
    const float* x      = (const float*)d_in[0];
    const int*   src0   = (const int*)d_in[1];
    const int*   dst0   = (const int*)d_in[2];
    const int*   src1   = (const int*)d_in[3];
    const int*   dst1   = (const int*)d_in[4];
    // d_in[5] = num_dst0, d_in[6] = num_dst1 (compile-time constants here)
    const float* Wself1  = (const float*)d_in[7];
    const float* Wneigh1 = (const float*)d_in[8];
    const float* b1      = (const float*)d_in[9];
    const float* Wself2  = (const float*)d_in[10];
    const float* Wneigh2 = (const float*)d_in[11];
    const float* b2      = (const float*)d_in[12];
    float* out = (float*)d_out;

    char* ws = (char*)d_ws;
    int* row0 = (int*)ws;                       // cN1+1 ints
    int* row1 = row0 + (cN1 + 1);               // cN2+1 ints
    size_t off = (size_t)((cN1 + 1) + (cN2 + 1)) * sizeof(int);
    off = (off + 1023) & ~(size_t)1023;
    float* h1 = (float*)(ws + off);             // cN1 x cH floats (~102.4 MB)

    // CSR row offsets from sorted dst arrays
    build_rows<<<(cN1 + 1 + 255) / 256, 256, 0, stream>>>(dst0, cE0, cN1, row0);
    build_rows<<<(cN2 + 1 + 255) / 256, 256, 0, stream>>>(dst1, cE1, cN2, row1);

    // Layer 1: x(200000x128) -> h1(100000x256), ReLU
    sage_layer<cIN, cH, true><<<(cN1 + 15) / 16, 256, 0, stream>>>(
        x, src0, row0, Wself1, Wneigh1, b1, h1, cN1);

    // Layer 2: h1(100000x256) -> out(50000x64)
    sage_layer<cH, cCLS, false><<<(cN2 + 15) / 16, 256, 0, stream>>>(
        h1, src1, row1, Wself2, Wneigh2, b2, out, cN2);
}

// Round 2
// 571.938 us; speedup vs baseline: 1.2968x; 1.2968x over previous
//
#include <hip/hip_runtime.h>

// Problem constants (fixed by the reference file)
constexpr int cN1  = 100000;   // num_dst layer 1
constexpr int cN2  = 50000;    // num_dst layer 2
constexpr int cE0  = 1600000;
constexpr int cE1  = 800000;
constexpr int cIN  = 128;      // IN_F
constexpr int cH   = 256;      // H_F
constexpr int cCLS = 64;       // N_CLS

// -------- CSR row-start construction: dst is sorted, lower_bound per dst --------
__global__ void build_rows(const int* __restrict__ dst, int E, int num_dst,
                           int* __restrict__ row_start) {
    int d = blockIdx.x * blockDim.x + threadIdx.x;
    if (d > num_dst) return;
    int lo = 0, hi = E;
    while (lo < hi) {
        int mid = (lo + hi) >> 1;
        if (dst[mid] < d) lo = mid + 1; else hi = mid;
    }
    row_start[d] = lo;
}

// -------- Gather + mean aggregation --------
// 16 lanes per dst row, 16 rows per 256-thread block. Edge loop unrolled x4
// so each lane keeps 4*NJ independent float4 gathers in flight (MLP).
// ACCUM=true: adds the mean into existing out (used for layer-2 epilogue).
template<int K, bool ACCUM>
__global__ __launch_bounds__(256) void agg_mean(
        const float* __restrict__ hsrc,      // [n_src][K]
        const int*   __restrict__ src_idx,   // [E]
        const int*   __restrict__ row_start, // [num_dst+1]
        float*       __restrict__ outn,      // [num_dst][K]
        int num_dst) {
    constexpr int K4 = K / 4;
    constexpr int NJ = K4 / 16;              // float4s per lane
    const int tid = threadIdx.x;
    const int g = tid >> 4, t = tid & 15;
    const int m = blockIdx.x * 16 + g;
    if (m >= num_dst) return;

    const float4* hs4 = (const float4*)hsrc;
    const int e0 = row_start[m], e1 = row_start[m + 1];

    float4 acc[NJ];
    #pragma unroll
    for (int j = 0; j < NJ; ++j) acc[j] = make_float4(0.f, 0.f, 0.f, 0.f);

    int e = e0;
    for (; e + 4 <= e1; e += 4) {
        const int s0 = src_idx[e + 0], s1 = src_idx[e + 1];
        const int s2 = src_idx[e + 2], s3 = src_idx[e + 3];
        const float4* p0 = hs4 + (size_t)s0 * K4 + t;
        const float4* p1 = hs4 + (size_t)s1 * K4 + t;
        const float4* p2 = hs4 + (size_t)s2 * K4 + t;
        const float4* p3 = hs4 + (size_t)s3 * K4 + t;
        #pragma unroll
        for (int j = 0; j < NJ; ++j) {
            float4 v0 = p0[j * 16], v1 = p1[j * 16];
            float4 v2 = p2[j * 16], v3 = p3[j * 16];
            acc[j].x += (v0.x + v1.x) + (v2.x + v3.x);
            acc[j].y += (v0.y + v1.y) + (v2.y + v3.y);
            acc[j].z += (v0.z + v1.z) + (v2.z + v3.z);
            acc[j].w += (v0.w + v1.w) + (v2.w + v3.w);
        }
    }
    for (; e < e1; ++e) {
        const int s = src_idx[e];
        const float4* p = hs4 + (size_t)s * K4 + t;
        #pragma unroll
        for (int j = 0; j < NJ; ++j) {
            float4 v = p[j * 16];
            acc[j].x += v.x; acc[j].y += v.y; acc[j].z += v.z; acc[j].w += v.w;
        }
    }

    const int deg = e1 - e0;
    const float inv = 1.0f / (float)(deg > 1 ? deg : 1);
    float4* o4 = (float4*)outn;
    #pragma unroll
    for (int j = 0; j < NJ; ++j) {
        const size_t idx = (size_t)m * K4 + t + j * 16;
        float4 v = make_float4(acc[j].x * inv, acc[j].y * inv,
                               acc[j].z * inv, acc[j].w * inv);
        if (ACCUM) {
            float4 o = o4[idx];
            v.x += o.x; v.y += o.y; v.z += o.z; v.w += o.w;
        }
        o4[idx] = v;
    }
}

// -------- Tiled fp32 GEMM with dual-source A (concat along K) --------
// C[M][N] = [A1 | A2] @ [W1 ; W2] (+bias) (+relu)
// A1 rows are K1 floats, A2 rows are K2 floats; K = K1+K2; BK divides K1 and K2.
// Block: 256 threads, tile BM x BN, per-thread TM x TN (TN==4, TM%4==0).
template<int BM, int BN, int BK, int TM, int TN, bool RELU, bool HAS_BIAS>
__global__ __launch_bounds__(256) void sgemm_cat(
        const float* __restrict__ A1, int K1,
        const float* __restrict__ A2, int K2,
        const float* __restrict__ W1,    // [K1][N]
        const float* __restrict__ W2,    // [K2][N]
        const float* __restrict__ bias,  // [N] or null
        float*       __restrict__ C,     // [M][N]
        int M, int N) {
    constexpr int RG = BM / TM;          // row groups
    constexpr int CG = BN / TN;          // col groups
    static_assert(RG * CG == 256, "thread tiling must equal block size");
    static_assert(TN == 4 && (TM % 4) == 0, "vectorized tiles");

    __shared__ float As[BK][BM + 4];     // +4 pad: staging scatter -> 2-way max
    __shared__ float Bs[BK][BN];

    const int tid = threadIdx.x;
    const int m0 = blockIdx.x * BM;
    const int n0 = blockIdx.y * BN;
    const int rg = tid / CG;
    const int cg = tid % CG;

    float acc[TM][TN];
    #pragma unroll
    for (int r = 0; r < TM; ++r)
        #pragma unroll
        for (int c = 0; c < TN; ++c) acc[r][c] = 0.f;

    const int K = K1 + K2;
    for (int kb = 0; kb < K; kb += BK) {
        const bool first = (kb < K1);            // wave-uniform
        const float* Ab = first ? A1 : A2;
        const float* Wb = first ? W1 : W2;
        const int kloc = first ? kb : kb - K1;
        const int lda  = first ? K1 : K2;

        // stage A tile (BM x BK), transposed into As[k][m]
        constexpr int AF4 = (BM * BK) / (256 * 4);
        #pragma unroll
        for (int f = 0; f < AF4; ++f) {
            const int i = tid + f * 256;
            const int row = i / (BK / 4);
            const int k4  = i % (BK / 4);
            const int gm = m0 + row;
            float4 v = make_float4(0.f, 0.f, 0.f, 0.f);
            if (gm < M) v = *(const float4*)(Ab + (size_t)gm * lda + kloc + k4 * 4);
            As[k4 * 4 + 0][row] = v.x;
            As[k4 * 4 + 1][row] = v.y;
            As[k4 * 4 + 2][row] = v.z;
            As[k4 * 4 + 3][row] = v.w;
        }
        // stage B tile (BK x BN), natural layout
        constexpr int BF4 = (BK * BN) / (256 * 4);
        #pragma unroll
        for (int f = 0; f < BF4; ++f) {
            const int i = tid + f * 256;
            const int kr = i / (BN / 4);
            const int n4 = i % (BN / 4);
            float4 v = *(const float4*)(Wb + (size_t)(kloc + kr) * N + n0 + n4 * 4);
            *(float4*)&Bs[kr][n4 * 4] = v;
        }
        __syncthreads();

        #pragma unroll
        for (int kk = 0; kk < BK; ++kk) {
            float a[TM], b[TN];
            #pragma unroll
            for (int r4 = 0; r4 < TM / 4; ++r4)
                *(float4*)&a[r4 * 4] = *(const float4*)&As[kk][rg * TM + r4 * 4];
            *(float4*)&b[0] = *(const float4*)&Bs[kk][cg * TN];
            #pragma unroll
            for (int r = 0; r < TM; ++r)
                #pragma unroll
                for (int c = 0; c < TN; ++c)
                    acc[r][c] += a[r] * b[c];
        }
        __syncthreads();
    }

    float4 bv = make_float4(0.f, 0.f, 0.f, 0.f);
    if (HAS_BIAS) bv = *(const float4*)(bias + n0 + cg * TN);
    #pragma unroll
    for (int r = 0; r < TM; ++r) {
        const int gm = m0 + rg * TM + r;
        if (gm >= M) continue;
        float4 o;
        o.x = acc[r][0] + bv.x;
        o.y = acc[r][1] + bv.y;
        o.z = acc[r][2] + bv.z;
        o.w = acc[r][3] + bv.w;
        if (RELU) {
            o.x = fmaxf(o.x, 0.f); o.y = fmaxf(o.y, 0.f);
            o.z = fmaxf(o.z, 0.f); o.w = fmaxf(o.w, 0.f);
        }
        *(float4*)(C + (size_t)gm * N + n0 + cg * TN) = o;
    }
}

extern "C" void kernel_launch(void* const* d_in, const int* in_sizes, int n_in,
                              void* d_out, int out_size, void* d_ws, size_t ws_size,
                              hipStream_t stream) {
    const float* x      = (const float*)d_in[0];
    const int*   src0   = (const int*)d_in[1];
    const int*   dst0   = (const int*)d_in[2];
    const int*   src1   = (const int*)d_in[3];
    const int*   dst1   = (const int*)d_in[4];
    const float* Wself1  = (const float*)d_in[7];
    const float* Wneigh1 = (const float*)d_in[8];
    const float* b1      = (const float*)d_in[9];
    const float* Wself2  = (const float*)d_in[10];
    const float* Wneigh2 = (const float*)d_in[11];
    const float* b2      = (const float*)d_in[12];
    float* out = (float*)d_out;

    // workspace layout
    char* ws = (char*)d_ws;
    int* row0 = (int*)ws;                       // cN1+1 ints
    int* row1 = row0 + (cN1 + 1);               // cN2+1 ints
    size_t off = (size_t)((cN1 + 1) + (cN2 + 1)) * sizeof(int);
    off = (off + 1023) & ~(size_t)1023;
    float* neigh1 = (float*)(ws + off);         // cN1 x cIN (51.2 MB); reused for z
    float* z = neigh1;                          // cN1 x cCLS (25.6 MB) after gemm1
    off += (size_t)cN1 * cIN * sizeof(float);
    float* h1 = (float*)(ws + off);             // cN1 x cH (102.4 MB)

    // CSR row offsets
    build_rows<<<(cN1 + 1 + 255) / 256, 256, 0, stream>>>(dst0, cE0, cN1, row0);
    build_rows<<<(cN2 + 1 + 255) / 256, 256, 0, stream>>>(dst1, cE1, cN2, row1);

    // Layer 1: aggregate x (128-dim), then h1 = relu([x|neigh] @ [Ws1;Wn1] + b1)
    agg_mean<cIN, false><<<(cN1 + 15) / 16, 256, 0, stream>>>(
        x, src0, row0, neigh1, cN1);
    sgemm_cat<64, 128, 16, 8, 4, true, true>
        <<<dim3((cN1 + 63) / 64, cH / 128), 256, 0, stream>>>(
        x, cIN, neigh1, cIN, Wself1, Wneigh1, b1, h1, cN1, cH);

    // Layer 2 (pre-transform): z = h1 @ Wn2 (all 100k rows);
    // out = h1[:50k] @ Ws2 + b2; then out += segmean(z)
    sgemm_cat<128, 64, 16, 8, 4, false, false>
        <<<dim3((cN1 + 127) / 128, 1), 256, 0, stream>>>(
        h1, cH, nullptr, 0, Wneigh2, nullptr, nullptr, z, cN1, cCLS);
    sgemm_cat<128, 64, 16, 8, 4, false, true>
        <<<dim3((cN2 + 127) / 128, 1), 256, 0, stream>>>(
        h1, cH, nullptr, 0, Wself2, nullptr, b2, out, cN2, cCLS);
    agg_mean<cCLS, true><<<(cN2 + 15) / 16, 256, 0, stream>>>(
        z, src1, row1, out, cN2);
}

// Round 3
// 347.249 us; speedup vs baseline: 2.1358x; 1.6471x over previous
//
#include <hip/hip_runtime.h>

// Problem constants (fixed by the reference file)
constexpr int cN1  = 100000;   // num_dst layer 1
constexpr int cN2  = 50000;    // num_dst layer 2
constexpr int cE0  = 1600000;
constexpr int cE1  = 800000;
constexpr int cIN  = 128;      // IN_F
constexpr int cH   = 256;      // H_F
constexpr int cCLS = 64;       // N_CLS

using bf16x8 = __attribute__((ext_vector_type(8))) short;   // 8 bf16 = 4 VGPRs
using f32x4  = __attribute__((ext_vector_type(4))) float;

__device__ __forceinline__ float bflo(unsigned int u) {
    union { unsigned int i; float f; } v; v.i = u << 16; return v.f;
}
__device__ __forceinline__ float bfhi(unsigned int u) {
    union { unsigned int i; float f; } v; v.i = u & 0xFFFF0000u; return v.f;
}
__device__ __forceinline__ unsigned int f2bf(float f) {   // RNE
    union { float f; unsigned int i; } v; v.f = f;
    return (v.i + 0x7FFFu + ((v.i >> 16) & 1u)) >> 16;
}

// -------- CSR row-start construction: dst is sorted, lower_bound per dst --------
__global__ void build_rows(const int* __restrict__ dst, int E, int num_dst,
                           int* __restrict__ row_start) {
    int d = blockIdx.x * blockDim.x + threadIdx.x;
    if (d > num_dst) return;
    int lo = 0, hi = E;
    while (lo < hi) {
        int mid = (lo + hi) >> 1;
        if (dst[mid] < d) lo = mid + 1; else hi = mid;
    }
    row_start[d] = lo;
}

// -------- fp32 -> bf16 bulk convert (8 elems/thread) --------
__global__ __launch_bounds__(256) void cvt_bf16(const float* __restrict__ in,
                                                unsigned short* __restrict__ out,
                                                int n8) {
    int i = blockIdx.x * 256 + threadIdx.x;
    if (i >= n8) return;
    const float4* p = (const float4*)in + (size_t)i * 2;
    float4 a = p[0], b = p[1];
    uint4 o;
    o.x = f2bf(a.x) | (f2bf(a.y) << 16);
    o.y = f2bf(a.z) | (f2bf(a.w) << 16);
    o.z = f2bf(b.x) | (f2bf(b.y) << 16);
    o.w = f2bf(b.z) | (f2bf(b.w) << 16);
    ((uint4*)out)[i] = o;
}

// -------- weight prep: bf16 + transpose, Wt[n][k] --------
// Wt1[256][256] = [Ws1;Wn1]^T ; Wt2n[64][256] = Wn2^T ; Wt2s[64][256] = Ws2^T
__global__ void cvt_w(const float* __restrict__ Ws1, const float* __restrict__ Wn1,
                      const float* __restrict__ Wn2, const float* __restrict__ Ws2,
                      unsigned short* __restrict__ Wt1,
                      unsigned short* __restrict__ Wt2n,
                      unsigned short* __restrict__ Wt2s) {
    int i = blockIdx.x * 256 + threadIdx.x;
    if (i < 256 * 256) {
        int n = i / 256, k = i % 256;
        float v = (k < 128) ? Ws1[k * 256 + n] : Wn1[(k - 128) * 256 + n];
        Wt1[n * 256 + k] = (unsigned short)f2bf(v);
    } else if (i < 256 * 256 + 64 * 256) {
        int j = i - 65536; int n = j / 256, k = j % 256;
        Wt2n[n * 256 + k] = (unsigned short)f2bf(Wn2[k * 64 + n]);
    } else if (i < 256 * 256 + 2 * 64 * 256) {
        int j = i - 65536 - 16384; int n = j / 256, k = j % 256;
        Wt2s[n * 256 + k] = (unsigned short)f2bf(Ws2[k * 64 + n]);
    }
}

// -------- Gather + mean aggregation over bf16 rows, fp32 accumulation --------
// Each lane handles 8 bf16 (16 B). K=128: 16 lanes/row; K=64: 8 lanes/row.
// ACCUM=false: write bf16 mean. ACCUM=true: add mean into fp32 out.
template<int K, bool ACCUM>
__global__ __launch_bounds__(256) void agg_bf16(
        const unsigned short* __restrict__ src,
        const int* __restrict__ sidx,
        const int* __restrict__ rows,
        void* __restrict__ outv, int num_dst) {
    constexpr int LPR = K / 8;          // lanes per row
    constexpr int RPB = 256 / LPR;      // rows per block
    constexpr int R4  = K / 8;          // uint4s per row
    const int tid = threadIdx.x;
    const int g = tid / LPR, t = tid % LPR;
    const int m = blockIdx.x * RPB + g;
    if (m >= num_dst) return;

    const uint4* s4 = (const uint4*)src;
    const int e0 = rows[m], e1 = rows[m + 1];
    float acc[8];
    #pragma unroll
    for (int j = 0; j < 8; ++j) acc[j] = 0.f;

    auto addv = [&](uint4 v) {
        acc[0] += bflo(v.x); acc[1] += bfhi(v.x);
        acc[2] += bflo(v.y); acc[3] += bfhi(v.y);
        acc[4] += bflo(v.z); acc[5] += bfhi(v.z);
        acc[6] += bflo(v.w); acc[7] += bfhi(v.w);
    };

    int e = e0;
    for (; e + 4 <= e1; e += 4) {
        int s0 = sidx[e], s1 = sidx[e + 1], s2 = sidx[e + 2], s3 = sidx[e + 3];
        uint4 v0 = s4[(size_t)s0 * R4 + t];
        uint4 v1 = s4[(size_t)s1 * R4 + t];
        uint4 v2 = s4[(size_t)s2 * R4 + t];
        uint4 v3 = s4[(size_t)s3 * R4 + t];
        addv(v0); addv(v1); addv(v2); addv(v3);
    }
    for (; e < e1; ++e) addv(s4[(size_t)sidx[e] * R4 + t]);

    const int deg = e1 - e0;
    const float inv = 1.0f / (float)(deg > 1 ? deg : 1);
    if (!ACCUM) {
        uint4 o;
        o.x = f2bf(acc[0] * inv) | (f2bf(acc[1] * inv) << 16);
        o.y = f2bf(acc[2] * inv) | (f2bf(acc[3] * inv) << 16);
        o.z = f2bf(acc[4] * inv) | (f2bf(acc[5] * inv) << 16);
        o.w = f2bf(acc[6] * inv) | (f2bf(acc[7] * inv) << 16);
        ((uint4*)outv)[(size_t)m * R4 + t] = o;
    } else {
        float* op = (float*)outv + (size_t)m * K + t * 8;
        float4 o0 = *(float4*)op, o1 = *(float4*)(op + 4);
        o0.x += acc[0] * inv; o0.y += acc[1] * inv;
        o0.z += acc[2] * inv; o0.w += acc[3] * inv;
        o1.x += acc[4] * inv; o1.y += acc[5] * inv;
        o1.z += acc[6] * inv; o1.w += acc[7] * inv;
        *(float4*)op = o0; *(float4*)(op + 4) = o1;
    }
}

// -------- bf16 MFMA GEMM: C = [A1|A2] @ Bt^T (+bias)(+relu) --------
// A1/A2: [M][K1], [M][K2] bf16 row-major (K-concat). Bt: [N][K] bf16 (W^T).
// 256 threads = 4 waves in 2x2; wave tile = (WM*16) x (WN*16); BK=32.
// mfma_f32_16x16x32_bf16: A[m=lane&15][k=(lane>>4)*8+j], B[k][n=lane&15],
// D col=lane&15, row=(lane>>4)*4+reg  (guide-verified mappings).
template<int BM, int BN, int WM, int WN, bool RELU, bool HASBIAS, bool OUTBF16>
__global__ __launch_bounds__(256) void gemm_mfma(
        const unsigned short* __restrict__ A1, int K1,
        const unsigned short* __restrict__ A2, int K2,
        const unsigned short* __restrict__ Bt,
        const float* __restrict__ bias,
        void* __restrict__ Cout, int M, int N) {
    static_assert(2 * WM * 16 == BM && 2 * WN * 16 == BN, "wave tiling");
    __shared__ unsigned short As[BM][40];   // 32 + 8 pad (bank spread, 16B aligned)
    __shared__ unsigned short Bs[BN][40];

    const int tid = threadIdx.x;
    const int m0 = blockIdx.x * BM, n0 = blockIdx.y * BN;
    const int lane = tid & 63, wave = tid >> 6;
    const int wrow = wave >> 1, wcol = wave & 1;
    const int quad = lane >> 4, l16 = lane & 15;
    const int K = K1 + K2;

    f32x4 acc[WM][WN];
    #pragma unroll
    for (int i = 0; i < WM; ++i)
        #pragma unroll
        for (int j = 0; j < WN; ++j)
            acc[i][j] = (f32x4){0.f, 0.f, 0.f, 0.f};

    for (int kb = 0; kb < K; kb += 32) {
        const unsigned short* Ab; int lda, kloc;
        if (kb < K1) { Ab = A1; lda = K1; kloc = kb; }
        else         { Ab = A2; lda = K2; kloc = kb - K1; }

        // stage A tile: BM rows x 32 bf16, 16B per thread-iter
        #pragma unroll
        for (int f = 0; f < (BM * 4) / 256; ++f) {
            int idx = tid + f * 256;
            int row = idx >> 2, q = idx & 3;
            int gm = m0 + row;
            uint4 v = make_uint4(0, 0, 0, 0);
            if (gm < M) v = *(const uint4*)(Ab + (size_t)gm * lda + kloc + q * 8);
            *(uint4*)&As[row][q * 8] = v;
        }
        // stage B tile: BN rows of Bt (no bounds needed: BN | N)
        #pragma unroll
        for (int f = 0; f < (BN * 4) / 256; ++f) {
            int idx = tid + f * 256;
            int row = idx >> 2, q = idx & 3;
            uint4 v = *(const uint4*)(Bt + (size_t)(n0 + row) * K + kb + q * 8);
            *(uint4*)&Bs[row][q * 8] = v;
        }
        __syncthreads();

        bf16x8 a[WM], b[WN];
        #pragma unroll
        for (int i = 0; i < WM; ++i)
            a[i] = *(const bf16x8*)&As[(wrow * WM + i) * 16 + l16][quad * 8];
        #pragma unroll
        for (int j = 0; j < WN; ++j)
            b[j] = *(const bf16x8*)&Bs[(wcol * WN + j) * 16 + l16][quad * 8];
        #pragma unroll
        for (int i = 0; i < WM; ++i)
            #pragma unroll
            for (int j = 0; j < WN; ++j)
                acc[i][j] = __builtin_amdgcn_mfma_f32_16x16x32_bf16(
                    a[i], b[j], acc[i][j], 0, 0, 0);
        __syncthreads();
    }

    // epilogue
    float bv[WN];
    #pragma unroll
    for (int j = 0; j < WN; ++j)
        bv[j] = HASBIAS ? bias[n0 + (wcol * WN + j) * 16 + l16] : 0.f;
    #pragma unroll
    for (int i = 0; i < WM; ++i) {
        #pragma unroll
        for (int r = 0; r < 4; ++r) {
            int gm = m0 + (wrow * WM + i) * 16 + quad * 4 + r;
            if (gm >= M) continue;
            #pragma unroll
            for (int j = 0; j < WN; ++j) {
                int gn = n0 + (wcol * WN + j) * 16 + l16;
                float v = acc[i][j][r] + bv[j];
                if (RELU) v = fmaxf(v, 0.f);
                if (OUTBF16)
                    ((unsigned short*)Cout)[(size_t)gm * N + gn] = (unsigned short)f2bf(v);
                else
                    ((float*)Cout)[(size_t)gm * N + gn] = v;
            }
        }
    }
}

extern "C" void kernel_launch(void* const* d_in, const int* in_sizes, int n_in,
                              void* d_out, int out_size, void* d_ws, size_t ws_size,
                              hipStream_t stream) {
    const float* x      = (const float*)d_in[0];
    const int*   src0   = (const int*)d_in[1];
    const int*   dst0   = (const int*)d_in[2];
    const int*   src1   = (const int*)d_in[3];
    const int*   dst1   = (const int*)d_in[4];
    const float* Wself1  = (const float*)d_in[7];
    const float* Wneigh1 = (const float*)d_in[8];
    const float* b1      = (const float*)d_in[9];
    const float* Wself2  = (const float*)d_in[10];
    const float* Wneigh2 = (const float*)d_in[11];
    const float* b2      = (const float*)d_in[12];
    float* out = (float*)d_out;

    // ---- workspace layout ----
    char* ws = (char*)d_ws;
    int* row0 = (int*)ws;                         // cN1+1
    int* row1 = row0 + (cN1 + 1);                 // cN2+1
    size_t off = (size_t)((cN1 + 1) + (cN2 + 1)) * sizeof(int);
    off = (off + 1023) & ~(size_t)1023;
    unsigned short* xb  = (unsigned short*)(ws + off);  off += (size_t)200000 * cIN * 2;
    unsigned short* nb  = (unsigned short*)(ws + off);  off += (size_t)cN1 * cIN * 2;
    unsigned short* h1b = (unsigned short*)(ws + off);  off += (size_t)cN1 * cH * 2;
    unsigned short* zb  = (unsigned short*)(ws + off);  off += (size_t)cN1 * cCLS * 2;
    unsigned short* Wt1  = (unsigned short*)(ws + off); off += 256 * 256 * 2;
    unsigned short* Wt2n = (unsigned short*)(ws + off); off += 64 * 256 * 2;
    unsigned short* Wt2s = (unsigned short*)(ws + off); off += 64 * 256 * 2;

    // CSR row offsets
    build_rows<<<(cN1 + 1 + 255) / 256, 256, 0, stream>>>(dst0, cE0, cN1, row0);
    build_rows<<<(cN2 + 1 + 255) / 256, 256, 0, stream>>>(dst1, cE1, cN2, row1);

    // dtype prep
    cvt_bf16<<<(200000 * cIN / 8 + 255) / 256, 256, 0, stream>>>(x, xb, 200000 * cIN / 8);
    cvt_w<<<(256 * 256 + 2 * 64 * 256 + 255) / 256, 256, 0, stream>>>(
        Wself1, Wneigh1, Wneigh2, Wself2, Wt1, Wt2n, Wt2s);

    // Layer 1: nb = segmean(xb); h1b = relu([xb|nb] @ Wt1^T + b1)
    agg_bf16<cIN, false><<<(cN1 + 15) / 16, 256, 0, stream>>>(
        xb, src0, row0, nb, cN1);
    gemm_mfma<128, 128, 4, 4, true, true, true>
        <<<dim3((cN1 + 127) / 128, cH / 128), 256, 0, stream>>>(
        xb, cIN, nb, cIN, Wt1, b1, h1b, cN1, cH);

    // Layer 2 (transform-then-aggregate): zb = h1b @ Wn2; out = h1b[:50k]@Ws2+b2;
    // out += segmean(zb)
    gemm_mfma<128, 64, 4, 2, false, false, true>
        <<<dim3((cN1 + 127) / 128, 1), 256, 0, stream>>>(
        h1b, cH, nullptr, 0, Wt2n, nullptr, zb, cN1, cCLS);
    gemm_mfma<128, 64, 4, 2, false, true, false>
        <<<dim3((cN2 + 127) / 128, 1), 256, 0, stream>>>(
        h1b, cH, nullptr, 0, Wt2s, b2, out, cN2, cCLS);
    agg_bf16<cCLS, true><<<(cN2 + 31) / 32, 256, 0, stream>>>(
        zb, src1, row1, out, cN2);
}